// Round 1
// baseline (934.869 us; speedup 1.0000x reference)
//
#include <hip/hip_runtime.h>

// ---------------------------------------------------------------------------
// CrossModalAttention: RoPE -> Q/K/V proj -> softmax(QK^T/sqrt(H)) V -> out proj
// B=4, S=2048, H=2048. All contractions via bf16 MFMA 16x16x32 (fp32 acc).
// ---------------------------------------------------------------------------

typedef __bf16 bf16_t;
typedef bf16_t bf16x8 __attribute__((ext_vector_type(8)));
typedef bf16_t bf16x4 __attribute__((ext_vector_type(4)));
typedef float  f32x4  __attribute__((ext_vector_type(4)));

#define BDIM 4
#define SDIM 2048
#define HDIM 2048

__device__ __forceinline__ void async_copy16(const bf16_t* g, bf16_t* l) {
  // global -> LDS direct DMA, 16B per lane; LDS dest = wave-uniform base + lane*16
  __builtin_amdgcn_global_load_lds(
      (__attribute__((address_space(1))) const void*)g,
      (__attribute__((address_space(3))) void*)l,
      16, 0, 0);
}

// ---------------------------------------------------------------------------
// RoPE on q,k (fp32 in) -> bf16 out.  One thread per (row, pair j / j+1024).
// ---------------------------------------------------------------------------
__global__ __launch_bounds__(256) void rope_kernel(
    const float* __restrict__ q, const float* __restrict__ k,
    bf16_t* __restrict__ qr, bf16_t* __restrict__ kr) {
  const int i = blockIdx.x * 256 + threadIdx.x;   // 0 .. B*S*1024-1
  const int j = i & 1023;
  const int row = i >> 10;                        // 0..8191
  const int s = row & (SDIM - 1);
  // inv_freq = 10000^(-j/1024) ; f = s * inv_freq  (fp32, matches ref)
  const float invf = exp2f(-(float)j * 0.012976281620653759f); // log2(1e4)/1024
  const float f = (float)s * invf;
  float sn, cs;
  sincosf(f, &sn, &cs);
  const long base = (long)row * HDIM;
  const float q1 = q[base + j], q2 = q[base + j + 1024];
  const float k1 = k[base + j], k2 = k[base + j + 1024];
  qr[base + j]        = (bf16_t)(q1 * cs - q2 * sn);
  qr[base + j + 1024] = (bf16_t)(q2 * cs + q1 * sn);
  kr[base + j]        = (bf16_t)(k1 * cs - k2 * sn);
  kr[base + j + 1024] = (bf16_t)(k2 * cs + k1 * sn);
}

// ---------------------------------------------------------------------------
// fp32 -> bf16 cast, 4 elems/thread
// ---------------------------------------------------------------------------
__global__ __launch_bounds__(256) void cast_kernel(
    const float* __restrict__ src, bf16_t* __restrict__ dst, int n4) {
  const int i = blockIdx.x * 256 + threadIdx.x;
  if (i >= n4) return;
  const float4 v = ((const float4*)src)[i];
  bf16x4 o;
  o[0] = (bf16_t)v.x; o[1] = (bf16_t)v.y; o[2] = (bf16_t)v.z; o[3] = (bf16_t)v.w;
  *(bf16x4*)&dst[(long)i * 4] = o;
}

// ---------------------------------------------------------------------------
// NT GEMM: C[M,N] = alpha * A[M,K] * Bt[N,K]^T + bias
// A,Bt bf16 row-major (lda=ldb=K); C fp32 or bf16 (ldc=N). Batched via blockIdx.z.
// 128x128 tile, BK=64, 4 waves (2x2), 4x4 16x16x32 MFMA tiles per wave.
// ---------------------------------------------------------------------------
template <bool OUTF32>
__global__ __launch_bounds__(256, 2) void gemm_bt(
    const bf16_t* __restrict__ A, const bf16_t* __restrict__ Bt,
    void* __restrict__ Cv, const float* __restrict__ bias,
    int M, int N, int K, float alpha,
    long sA, long sB, long sC) {
  __shared__ __align__(16) bf16_t As[128 * 64];
  __shared__ __align__(16) bf16_t Bs[128 * 64];
  const int z = blockIdx.z;
  A  += (long)z * sA;
  Bt += (long)z * sB;
  const int tid  = threadIdx.x;
  const int lane = tid & 63;
  const int wave = tid >> 6;
  const int wm = (wave >> 1) * 64;   // wave row offset in tile
  const int wn = (wave & 1) * 64;    // wave col offset in tile
  const int m0 = blockIdx.y * 128;
  const int n0 = blockIdx.x * 128;
  const int lrow = lane & 15;
  const int quad = lane >> 4;

  f32x4 acc[4][4] = {};

  const long aBase = (long)m0 * K;
  const long bBase = (long)n0 * K;

  for (int k0 = 0; k0 < K; k0 += 64) {
#pragma unroll
    for (int i = 0; i < 4; ++i) {
      const int c  = wave * 4 + i;        // chunk 0..15, 512 elems each
      const int e  = c * 512 + lane * 8;  // elem index in 128x64 tile
      const int r  = e >> 6;
      const int cc = e & 63;
      async_copy16(A  + aBase + (long)r * K + k0 + cc, As + c * 512);
      async_copy16(Bt + bBase + (long)r * K + k0 + cc, Bs + c * 512);
    }
    __syncthreads();
#pragma unroll
    for (int ks = 0; ks < 64; ks += 32) {
      bf16x8 af[4], bfr[4];
#pragma unroll
      for (int t = 0; t < 4; ++t)
        af[t] = *(const bf16x8*)&As[(wm + t * 16 + lrow) * 64 + ks + quad * 8];
#pragma unroll
      for (int t = 0; t < 4; ++t)
        bfr[t] = *(const bf16x8*)&Bs[(wn + t * 16 + lrow) * 64 + ks + quad * 8];
#pragma unroll
      for (int mt = 0; mt < 4; ++mt)
#pragma unroll
        for (int nt = 0; nt < 4; ++nt)
          acc[mt][nt] = __builtin_amdgcn_mfma_f32_16x16x32_bf16(
              af[mt], bfr[nt], acc[mt][nt], 0, 0, 0);
    }
    __syncthreads();
  }

  // epilogue: D[row=quad*4+r][col=lane&15] per 16x16 tile (HW-verified layout)
#pragma unroll
  for (int mt = 0; mt < 4; ++mt) {
#pragma unroll
    for (int nt = 0; nt < 4; ++nt) {
      const int col = n0 + wn + nt * 16 + lrow;
      const float bv = bias ? bias[col] : 0.0f;
#pragma unroll
      for (int r = 0; r < 4; ++r) {
        const int row = m0 + wm + mt * 16 + quad * 4 + r;
        const float v = acc[mt][nt][r] * alpha + bv;
        if (OUTF32)
          ((float*)Cv)[(long)z * sC + (long)row * N + col] = v;
        else
          ((bf16_t*)Cv)[(long)z * sC + (long)row * N + col] = (bf16_t)v;
      }
    }
  }
}

// ---------------------------------------------------------------------------
// Row softmax: fp32 scores [rows,2048] -> bf16 probs. 256 thr/row, 8 elems/thr.
// ---------------------------------------------------------------------------
__global__ __launch_bounds__(256) void softmax_kernel(
    const float* __restrict__ Sc, bf16_t* __restrict__ P) {
  const long row = blockIdx.x;
  const float* src = Sc + row * SDIM;
  bf16_t* dst = P + row * SDIM;
  const int tid = threadIdx.x;
  float4 a = ((const float4*)src)[tid];
  float4 b = ((const float4*)src)[tid + 256];
  float m = fmaxf(fmaxf(fmaxf(a.x, a.y), fmaxf(a.z, a.w)),
                  fmaxf(fmaxf(b.x, b.y), fmaxf(b.z, b.w)));
#pragma unroll
  for (int off = 32; off; off >>= 1) m = fmaxf(m, __shfl_xor(m, off));
  __shared__ float redm[4], reds[4];
  const int wave = tid >> 6, lane = tid & 63;
  if (lane == 0) redm[wave] = m;
  __syncthreads();
  m = fmaxf(fmaxf(redm[0], redm[1]), fmaxf(redm[2], redm[3]));
  a.x = __expf(a.x - m); a.y = __expf(a.y - m);
  a.z = __expf(a.z - m); a.w = __expf(a.w - m);
  b.x = __expf(b.x - m); b.y = __expf(b.y - m);
  b.z = __expf(b.z - m); b.w = __expf(b.w - m);
  float s = a.x + a.y + a.z + a.w + b.x + b.y + b.z + b.w;
#pragma unroll
  for (int off = 32; off; off >>= 1) s += __shfl_xor(s, off);
  if (lane == 0) reds[wave] = s;
  __syncthreads();
  s = reds[0] + reds[1] + reds[2] + reds[3];
  const float inv = 1.0f / s;
  bf16x4 o0, o1;
  o0[0] = (bf16_t)(a.x * inv); o0[1] = (bf16_t)(a.y * inv);
  o0[2] = (bf16_t)(a.z * inv); o0[3] = (bf16_t)(a.w * inv);
  o1[0] = (bf16_t)(b.x * inv); o1[1] = (bf16_t)(b.y * inv);
  o1[2] = (bf16_t)(b.z * inv); o1[3] = (bf16_t)(b.w * inv);
  *(bf16x4*)&dst[tid * 4] = o0;
  *(bf16x4*)&dst[1024 + tid * 4] = o1;
}

// ---------------------------------------------------------------------------
// bf16 transpose per batch: in [rows,cols] -> out [cols,rows]. 64x64 LDS tiles.
// ---------------------------------------------------------------------------
__global__ __launch_bounds__(256) void transpose_bf16(
    const bf16_t* __restrict__ in, bf16_t* __restrict__ out, int rows, int cols) {
  __shared__ bf16_t tile[64][72];  // 72*2=144B row stride, 16B-aligned
  const long bo = (long)blockIdx.z * rows * cols;
  in += bo; out += bo;
  const int c0 = blockIdx.x * 64, r0 = blockIdx.y * 64;
  const int t = threadIdx.x;
  const int lr = t >> 3;          // 0..31
  const int lc = (t & 7) * 8;     // 0..56
#pragma unroll
  for (int i = 0; i < 2; ++i) {
    const int r = lr + i * 32;
    bf16x8 v = *(const bf16x8*)&in[(long)(r0 + r) * cols + c0 + lc];
    *(bf16x8*)&tile[r][lc] = v;
  }
  __syncthreads();
#pragma unroll
  for (int i = 0; i < 2; ++i) {
    const int r = lr + i * 32;
    bf16x8 v;
#pragma unroll
    for (int j = 0; j < 8; ++j) v[j] = tile[lc + j][r];
    *(bf16x8*)&out[(long)(c0 + r) * rows + r0 + lc] = v;
  }
}

// ---------------------------------------------------------------------------
extern "C" void kernel_launch(void* const* d_in, const int* in_sizes, int n_in,
                              void* d_out, int out_size, void* d_ws, size_t ws_size,
                              hipStream_t stream) {
  const float* q_in = (const float*)d_in[0];
  const float* k_in = (const float*)d_in[1];
  const float* v_in = (const float*)d_in[2];
  const float* Wq = (const float*)d_in[3];
  const float* bq = (const float*)d_in[4];
  const float* Wk = (const float*)d_in[5];
  const float* bk = (const float*)d_in[6];
  const float* Wv = (const float*)d_in[7];
  const float* bv = (const float*)d_in[8];
  const float* Wo = (const float*)d_in[9];
  const float* bo = (const float*)d_in[10];
  float* out = (float*)d_out;

  const size_t ELE  = (size_t)BDIM * SDIM * HDIM;   // 16,777,216
  const size_t WELE = (size_t)HDIM * HDIM;          // 4,194,304
  const size_t SEG  = ELE * 2;                      // 33,554,432 B per bf16 [B,S,H]

  uint8_t* w = (uint8_t*)d_ws;
  bf16_t* qr  = (bf16_t*)(w + 0 * SEG);
  bf16_t* kr  = (bf16_t*)(w + 1 * SEG);
  bf16_t* vb  = (bf16_t*)(w + 2 * SEG);
  bf16_t* Wb  = (bf16_t*)(w + 3 * SEG);   // Wq,Wk,Wv,Wo bf16 consecutive
  bf16_t* qp  = (bf16_t*)(w + 4 * SEG);
  bf16_t* kp  = (bf16_t*)(w + 5 * SEG);
  bf16_t* vp  = (bf16_t*)(w + 6 * SEG);
  // aliases (regions dead by the time they're written):
  float*  scores = (float*)(w + 0 * SEG);   // 67 MB over qr+kr
  bf16_t* probs  = (bf16_t*)(w + 2 * SEG);  // over vb
  bf16_t* vpT    = (bf16_t*)(w + 4 * SEG);  // over qp
  bf16_t* ctx    = (bf16_t*)(w + 5 * SEG);  // over kp

  bf16_t* Wqb = Wb + 0 * WELE;
  bf16_t* Wkb = Wb + 1 * WELE;
  bf16_t* Wvb = Wb + 2 * WELE;
  bf16_t* Wob = Wb + 3 * WELE;

  const dim3 blk(256);
  const long SH = (long)SDIM * HDIM;   // per-batch activation stride (elems)
  const long SS = (long)SDIM * SDIM;   // per-batch score stride (elems)

  // 1. RoPE q,k -> bf16
  rope_kernel<<<dim3(ELE / 2 / 256), blk, 0, stream>>>(q_in, k_in, qr, kr);
  // 2. casts
  cast_kernel<<<dim3(ELE / 4 / 256), blk, 0, stream>>>(v_in, vb, (int)(ELE / 4));
  cast_kernel<<<dim3(WELE / 4 / 256), blk, 0, stream>>>(Wq, Wqb, (int)(WELE / 4));
  cast_kernel<<<dim3(WELE / 4 / 256), blk, 0, stream>>>(Wk, Wkb, (int)(WELE / 4));
  cast_kernel<<<dim3(WELE / 4 / 256), blk, 0, stream>>>(Wv, Wvb, (int)(WELE / 4));
  cast_kernel<<<dim3(WELE / 4 / 256), blk, 0, stream>>>(Wo, Wob, (int)(WELE / 4));
  // 3-5. projections: [8192,2048] x [2048,2048]^T + bias -> bf16
  gemm_bt<false><<<dim3(16, 64, 1), blk, 0, stream>>>(qr, Wqb, qp, bq,
      BDIM * SDIM, HDIM, HDIM, 1.0f, 0, 0, 0);
  gemm_bt<false><<<dim3(16, 64, 1), blk, 0, stream>>>(kr, Wkb, kp, bk,
      BDIM * SDIM, HDIM, HDIM, 1.0f, 0, 0, 0);
  gemm_bt<false><<<dim3(16, 64, 1), blk, 0, stream>>>(vb, Wvb, vp, bv,
      BDIM * SDIM, HDIM, HDIM, 1.0f, 0, 0, 0);
  // 6. scores = qp kp^T / sqrt(H)  (fp32 out, batched)
  gemm_bt<true><<<dim3(16, 16, BDIM), blk, 0, stream>>>(qp, kp, scores, nullptr,
      SDIM, SDIM, HDIM, 0.022097086912079612f, SH, SH, SS);
  // 7. softmax rows -> bf16 probs
  softmax_kernel<<<dim3(BDIM * SDIM), blk, 0, stream>>>(scores, probs);
  // 8. vp -> vp^T per batch
  transpose_bf16<<<dim3(32, 32, BDIM), blk, 0, stream>>>(vp, vpT, SDIM, HDIM);
  // 9. ctx = probs @ vp  ==  NT(probs, vpT)
  gemm_bt<false><<<dim3(16, 16, BDIM), blk, 0, stream>>>(probs, vpT, ctx, nullptr,
      SDIM, HDIM, SDIM, 1.0f, SS, SH, SH);
  // 10. out = ctx Wo^T + bo  (fp32 -> d_out)
  gemm_bt<true><<<dim3(16, 64, 1), blk, 0, stream>>>(ctx, Wob, out, bo,
      BDIM * SDIM, HDIM, HDIM, 1.0f, 0, 0, 0);
}

// Round 2
// 761.515 us; speedup vs baseline: 1.2276x; 1.2276x over previous
//
#include <hip/hip_runtime.h>

// ---------------------------------------------------------------------------
// CrossModalAttention: RoPE -> Q/K/V proj -> softmax(QK^T/sqrt(H)) V -> out proj
// B=4, S=2048, H=2048. All contractions via bf16 MFMA 16x16x32 (fp32 acc).
// R1 change: XOR-swizzled LDS staging (global source permuted, since
// global_load_lds fixes LDS dest = base + lane*16) to kill the 16-way
// bank conflict on fragment ds_read_b128.
// ---------------------------------------------------------------------------

typedef __bf16 bf16_t;
typedef bf16_t bf16x8 __attribute__((ext_vector_type(8)));
typedef bf16_t bf16x4 __attribute__((ext_vector_type(4)));
typedef float  f32x4  __attribute__((ext_vector_type(4)));

#define BDIM 4
#define SDIM 2048
#define HDIM 2048

__device__ __forceinline__ void async_copy16(const bf16_t* g, bf16_t* l) {
  __builtin_amdgcn_global_load_lds(
      (__attribute__((address_space(1))) const void*)g,
      (__attribute__((address_space(3))) void*)l,
      16, 0, 0);
}

// ---------------------------------------------------------------------------
// RoPE on q,k (fp32 in) -> bf16 out.  One thread per (row, pair j / j+1024).
// ---------------------------------------------------------------------------
__global__ __launch_bounds__(256) void rope_kernel(
    const float* __restrict__ q, const float* __restrict__ k,
    bf16_t* __restrict__ qr, bf16_t* __restrict__ kr) {
  const int i = blockIdx.x * 256 + threadIdx.x;   // 0 .. B*S*1024-1
  const int j = i & 1023;
  const int row = i >> 10;                        // 0..8191
  const int s = row & (SDIM - 1);
  const float invf = exp2f(-(float)j * 0.012976281620653759f); // log2(1e4)/1024
  const float f = (float)s * invf;
  float sn, cs;
  sincosf(f, &sn, &cs);
  const long base = (long)row * HDIM;
  const float q1 = q[base + j], q2 = q[base + j + 1024];
  const float k1 = k[base + j], k2 = k[base + j + 1024];
  qr[base + j]        = (bf16_t)(q1 * cs - q2 * sn);
  qr[base + j + 1024] = (bf16_t)(q2 * cs + q1 * sn);
  kr[base + j]        = (bf16_t)(k1 * cs - k2 * sn);
  kr[base + j + 1024] = (bf16_t)(k2 * cs + k1 * sn);
}

// ---------------------------------------------------------------------------
// fp32 -> bf16 cast, 4 elems/thread
// ---------------------------------------------------------------------------
__global__ __launch_bounds__(256) void cast_kernel(
    const float* __restrict__ src, bf16_t* __restrict__ dst, int n4) {
  const int i = blockIdx.x * 256 + threadIdx.x;
  if (i >= n4) return;
  const float4 v = ((const float4*)src)[i];
  bf16x4 o;
  o[0] = (bf16_t)v.x; o[1] = (bf16_t)v.y; o[2] = (bf16_t)v.z; o[3] = (bf16_t)v.w;
  *(bf16x4*)&dst[(long)i * 4] = o;
}

// ---------------------------------------------------------------------------
// NT GEMM: C[M,N] = alpha * A[M,K] * Bt[N,K]^T + bias
// A,Bt bf16 row-major (lda=ldb=K); C fp32 or bf16 (ldc=N). Batched via blockIdx.z.
// 128x128 tile, BK=64, 4 waves (2x2), 4x4 16x16x32 MFMA tiles per wave.
// LDS layout: LDS(row, chunk j) = global(row, chunk j ^ (row&7)), chunks = 16B.
// ---------------------------------------------------------------------------
template <bool OUTF32>
__global__ __launch_bounds__(256, 2) void gemm_bt(
    const bf16_t* __restrict__ A, const bf16_t* __restrict__ Bt,
    void* __restrict__ Cv, const float* __restrict__ bias,
    int M, int N, int K, float alpha,
    long sA, long sB, long sC) {
  __shared__ __align__(16) bf16_t As[128 * 64];
  __shared__ __align__(16) bf16_t Bs[128 * 64];
  const int z = blockIdx.z;
  A  += (long)z * sA;
  Bt += (long)z * sB;
  const int tid  = threadIdx.x;
  const int lane = tid & 63;
  const int wave = tid >> 6;
  const int wm = (wave >> 1) * 64;   // wave row offset in tile
  const int wn = (wave & 1) * 64;    // wave col offset in tile
  const int m0 = blockIdx.y * 128;
  const int n0 = blockIdx.x * 128;
  const int lrow = lane & 15;
  const int quad = lane >> 4;
  const int swz  = lrow & 7;         // row&7 for all fragment rows this lane reads

  f32x4 acc[4][4] = {};

  const long aBase = (long)m0 * K;
  const long bBase = (long)n0 * K;

  // staging source swizzle: lane writes LDS chunk (lane&7) of row c*8+(lane>>3);
  // load global chunk (lane&7) ^ (lane>>3) so LDS(r,j)=global(r, j^(r&7)).
  const int rl  = lane >> 3;                 // row within 8-row chunk
  const int ccs = ((lane & 7) ^ rl) * 8;     // swizzled global column (elems)

  for (int k0 = 0; k0 < K; k0 += 64) {
#pragma unroll
    for (int i = 0; i < 4; ++i) {
      const int c = wave * 4 + i;            // chunk 0..15, 512 elems each
      const int r = c * 8 + rl;
      async_copy16(A  + aBase + (long)r * K + k0 + ccs, As + c * 512);
      async_copy16(Bt + bBase + (long)r * K + k0 + ccs, Bs + c * 512);
    }
    __syncthreads();
#pragma unroll
    for (int ks = 0; ks < 64; ks += 32) {
      bf16x8 af[4], bfr[4];
      const int cg = (ks >> 3) + quad;       // desired global 16B-chunk index
      const int j  = (cg ^ swz) * 8;         // swizzled LDS column (elems)
#pragma unroll
      for (int t = 0; t < 4; ++t)
        af[t] = *(const bf16x8*)&As[(wm + t * 16 + lrow) * 64 + j];
#pragma unroll
      for (int t = 0; t < 4; ++t)
        bfr[t] = *(const bf16x8*)&Bs[(wn + t * 16 + lrow) * 64 + j];
#pragma unroll
      for (int mt = 0; mt < 4; ++mt)
#pragma unroll
        for (int nt = 0; nt < 4; ++nt)
          acc[mt][nt] = __builtin_amdgcn_mfma_f32_16x16x32_bf16(
              af[mt], bfr[nt], acc[mt][nt], 0, 0, 0);
    }
    __syncthreads();
  }

  // epilogue: D[row=quad*4+r][col=lane&15] per 16x16 tile (HW-verified layout)
#pragma unroll
  for (int mt = 0; mt < 4; ++mt) {
#pragma unroll
    for (int nt = 0; nt < 4; ++nt) {
      const int col = n0 + wn + nt * 16 + lrow;
      const float bv = bias ? bias[col] : 0.0f;
#pragma unroll
      for (int r = 0; r < 4; ++r) {
        const int row = m0 + wm + mt * 16 + quad * 4 + r;
        const float v = acc[mt][nt][r] * alpha + bv;
        if (OUTF32)
          ((float*)Cv)[(long)z * sC + (long)row * N + col] = v;
        else
          ((bf16_t*)Cv)[(long)z * sC + (long)row * N + col] = (bf16_t)v;
      }
    }
  }
}

// ---------------------------------------------------------------------------
// Row softmax: fp32 scores [rows,2048] -> bf16 probs. 256 thr/row, 8 elems/thr.
// ---------------------------------------------------------------------------
__global__ __launch_bounds__(256) void softmax_kernel(
    const float* __restrict__ Sc, bf16_t* __restrict__ P) {
  const long row = blockIdx.x;
  const float* src = Sc + row * SDIM;
  bf16_t* dst = P + row * SDIM;
  const int tid = threadIdx.x;
  float4 a = ((const float4*)src)[tid];
  float4 b = ((const float4*)src)[tid + 256];
  float m = fmaxf(fmaxf(fmaxf(a.x, a.y), fmaxf(a.z, a.w)),
                  fmaxf(fmaxf(b.x, b.y), fmaxf(b.z, b.w)));
#pragma unroll
  for (int off = 32; off; off >>= 1) m = fmaxf(m, __shfl_xor(m, off));
  __shared__ float redm[4], reds[4];
  const int wave = tid >> 6, lane = tid & 63;
  if (lane == 0) redm[wave] = m;
  __syncthreads();
  m = fmaxf(fmaxf(redm[0], redm[1]), fmaxf(redm[2], redm[3]));
  a.x = __expf(a.x - m); a.y = __expf(a.y - m);
  a.z = __expf(a.z - m); a.w = __expf(a.w - m);
  b.x = __expf(b.x - m); b.y = __expf(b.y - m);
  b.z = __expf(b.z - m); b.w = __expf(b.w - m);
  float s = a.x + a.y + a.z + a.w + b.x + b.y + b.z + b.w;
#pragma unroll
  for (int off = 32; off; off >>= 1) s += __shfl_xor(s, off);
  if (lane == 0) reds[wave] = s;
  __syncthreads();
  s = reds[0] + reds[1] + reds[2] + reds[3];
  const float inv = 1.0f / s;
  bf16x4 o0, o1;
  o0[0] = (bf16_t)(a.x * inv); o0[1] = (bf16_t)(a.y * inv);
  o0[2] = (bf16_t)(a.z * inv); o0[3] = (bf16_t)(a.w * inv);
  o1[0] = (bf16_t)(b.x * inv); o1[1] = (bf16_t)(b.y * inv);
  o1[2] = (bf16_t)(b.z * inv); o1[3] = (bf16_t)(b.w * inv);
  *(bf16x4*)&dst[tid * 4] = o0;
  *(bf16x4*)&dst[1024 + tid * 4] = o1;
}

// ---------------------------------------------------------------------------
// bf16 transpose per batch: in [rows,cols] -> out [cols,rows]. 64x64 LDS tiles.
// ---------------------------------------------------------------------------
__global__ __launch_bounds__(256) void transpose_bf16(
    const bf16_t* __restrict__ in, bf16_t* __restrict__ out, int rows, int cols) {
  __shared__ bf16_t tile[64][72];  // 72*2=144B row stride, breaks pow2 banks
  const long bo = (long)blockIdx.z * rows * cols;
  in += bo; out += bo;
  const int c0 = blockIdx.x * 64, r0 = blockIdx.y * 64;
  const int t = threadIdx.x;
  const int lr = t >> 3;          // 0..31
  const int lc = (t & 7) * 8;     // 0..56
#pragma unroll
  for (int i = 0; i < 2; ++i) {
    const int r = lr + i * 32;
    bf16x8 v = *(const bf16x8*)&in[(long)(r0 + r) * cols + c0 + lc];
    *(bf16x8*)&tile[r][lc] = v;
  }
  __syncthreads();
#pragma unroll
  for (int i = 0; i < 2; ++i) {
    const int r = lr + i * 32;
    bf16x8 v;
#pragma unroll
    for (int j = 0; j < 8; ++j) v[j] = tile[lc + j][r];
    *(bf16x8*)&out[(long)(c0 + r) * rows + r0 + lc] = v;
  }
}

// ---------------------------------------------------------------------------
extern "C" void kernel_launch(void* const* d_in, const int* in_sizes, int n_in,
                              void* d_out, int out_size, void* d_ws, size_t ws_size,
                              hipStream_t stream) {
  const float* q_in = (const float*)d_in[0];
  const float* k_in = (const float*)d_in[1];
  const float* v_in = (const float*)d_in[2];
  const float* Wq = (const float*)d_in[3];
  const float* bq = (const float*)d_in[4];
  const float* Wk = (const float*)d_in[5];
  const float* bk = (const float*)d_in[6];
  const float* Wv = (const float*)d_in[7];
  const float* bv = (const float*)d_in[8];
  const float* Wo = (const float*)d_in[9];
  const float* bo = (const float*)d_in[10];
  float* out = (float*)d_out;

  const size_t ELE  = (size_t)BDIM * SDIM * HDIM;   // 16,777,216
  const size_t WELE = (size_t)HDIM * HDIM;          // 4,194,304
  const size_t SEG  = ELE * 2;                      // 33,554,432 B per bf16 [B,S,H]

  uint8_t* w = (uint8_t*)d_ws;
  bf16_t* qr  = (bf16_t*)(w + 0 * SEG);
  bf16_t* kr  = (bf16_t*)(w + 1 * SEG);
  bf16_t* vb  = (bf16_t*)(w + 2 * SEG);
  bf16_t* Wb  = (bf16_t*)(w + 3 * SEG);   // Wq,Wk,Wv,Wo bf16 consecutive
  bf16_t* qp  = (bf16_t*)(w + 4 * SEG);
  bf16_t* kp  = (bf16_t*)(w + 5 * SEG);
  bf16_t* vp  = (bf16_t*)(w + 6 * SEG);
  // aliases (regions dead by the time they're written):
  float*  scores = (float*)(w + 0 * SEG);   // 67 MB over qr+kr
  bf16_t* probs  = (bf16_t*)(w + 2 * SEG);  // over vb
  bf16_t* vpT    = (bf16_t*)(w + 4 * SEG);  // over qp
  bf16_t* ctx    = (bf16_t*)(w + 5 * SEG);  // over kp

  bf16_t* Wqb = Wb + 0 * WELE;
  bf16_t* Wkb = Wb + 1 * WELE;
  bf16_t* Wvb = Wb + 2 * WELE;
  bf16_t* Wob = Wb + 3 * WELE;

  const dim3 blk(256);
  const long SH = (long)SDIM * HDIM;   // per-batch activation stride (elems)
  const long SS = (long)SDIM * SDIM;   // per-batch score stride (elems)

  // 1. RoPE q,k -> bf16
  rope_kernel<<<dim3(ELE / 2 / 256), blk, 0, stream>>>(q_in, k_in, qr, kr);
  // 2. casts
  cast_kernel<<<dim3(ELE / 4 / 256), blk, 0, stream>>>(v_in, vb, (int)(ELE / 4));
  cast_kernel<<<dim3(WELE / 4 / 256), blk, 0, stream>>>(Wq, Wqb, (int)(WELE / 4));
  cast_kernel<<<dim3(WELE / 4 / 256), blk, 0, stream>>>(Wk, Wkb, (int)(WELE / 4));
  cast_kernel<<<dim3(WELE / 4 / 256), blk, 0, stream>>>(Wv, Wvb, (int)(WELE / 4));
  cast_kernel<<<dim3(WELE / 4 / 256), blk, 0, stream>>>(Wo, Wob, (int)(WELE / 4));
  // 3-5. projections: [8192,2048] x [2048,2048]^T + bias -> bf16
  gemm_bt<false><<<dim3(16, 64, 1), blk, 0, stream>>>(qr, Wqb, qp, bq,
      BDIM * SDIM, HDIM, HDIM, 1.0f, 0, 0, 0);
  gemm_bt<false><<<dim3(16, 64, 1), blk, 0, stream>>>(kr, Wkb, kp, bk,
      BDIM * SDIM, HDIM, HDIM, 1.0f, 0, 0, 0);
  gemm_bt<false><<<dim3(16, 64, 1), blk, 0, stream>>>(vb, Wvb, vp, bv,
      BDIM * SDIM, HDIM, HDIM, 1.0f, 0, 0, 0);
  // 6. scores = qp kp^T / sqrt(H)  (fp32 out, batched)
  gemm_bt<true><<<dim3(16, 16, BDIM), blk, 0, stream>>>(qp, kp, scores, nullptr,
      SDIM, SDIM, HDIM, 0.022097086912079612f, SH, SH, SS);
  // 7. softmax rows -> bf16 probs
  softmax_kernel<<<dim3(BDIM * SDIM), blk, 0, stream>>>(scores, probs);
  // 8. vp -> vp^T per batch
  transpose_bf16<<<dim3(32, 32, BDIM), blk, 0, stream>>>(vp, vpT, SDIM, HDIM);
  // 9. ctx = probs @ vp  ==  NT(probs, vpT)
  gemm_bt<false><<<dim3(16, 16, BDIM), blk, 0, stream>>>(probs, vpT, ctx, nullptr,
      SDIM, HDIM, SDIM, 1.0f, SS, SH, SH);
  // 10. out = ctx Wo^T + bo  (fp32 -> d_out)
  gemm_bt<true><<<dim3(16, 64, 1), blk, 0, stream>>>(ctx, Wob, out, bo,
      BDIM * SDIM, HDIM, HDIM, 1.0f, 0, 0, 0);
}

// Round 3
// 709.304 us; speedup vs baseline: 1.3180x; 1.0736x over previous
//
#include <hip/hip_runtime.h>

// ---------------------------------------------------------------------------
// CrossModalAttention: RoPE -> Q/K/V proj -> softmax(QK^T/sqrt(H)) V -> out proj
// B=4, S=2048, H=2048. All contractions via bf16 MFMA 16x16x32 (fp32 acc).
// R1: XOR-swizzled LDS staging -> 0 bank conflicts, GEMMs at ~838 TF (plateau).
// R2: fuse elementwise (rope+vcast, 4 wcasts), transpose fused into V-proj
//     epilogue (OMODE 2), scores carried as bf16 (halves softmax traffic).
// ---------------------------------------------------------------------------

typedef __bf16 bf16_t;
typedef bf16_t bf16x8 __attribute__((ext_vector_type(8)));
typedef bf16_t bf16x4 __attribute__((ext_vector_type(4)));
typedef float  f32x4  __attribute__((ext_vector_type(4)));

#define BDIM 4
#define SDIM 2048
#define HDIM 2048

__device__ __forceinline__ void async_copy16(const bf16_t* g, bf16_t* l) {
  __builtin_amdgcn_global_load_lds(
      (__attribute__((address_space(1))) const void*)g,
      (__attribute__((address_space(3))) void*)l,
      16, 0, 0);
}

// ---------------------------------------------------------------------------
// Fused prep: RoPE on q,k + cast v. One thread per (row, pair j/j+1024).
// ---------------------------------------------------------------------------
__global__ __launch_bounds__(256) void prep_kernel(
    const float* __restrict__ q, const float* __restrict__ k,
    const float* __restrict__ v,
    bf16_t* __restrict__ qr, bf16_t* __restrict__ kr, bf16_t* __restrict__ vb) {
  const int i = blockIdx.x * 256 + threadIdx.x;   // 0 .. B*S*1024-1
  const int j = i & 1023;
  const int row = i >> 10;                        // 0..8191
  const int s = row & (SDIM - 1);
  const float invf = exp2f(-(float)j * 0.012976281620653759f); // log2(1e4)/1024
  const float f = (float)s * invf;
  float sn, cs;
  sincosf(f, &sn, &cs);
  const long base = (long)row * HDIM;
  const float q1 = q[base + j], q2 = q[base + j + 1024];
  const float k1 = k[base + j], k2 = k[base + j + 1024];
  qr[base + j]        = (bf16_t)(q1 * cs - q2 * sn);
  qr[base + j + 1024] = (bf16_t)(q2 * cs + q1 * sn);
  kr[base + j]        = (bf16_t)(k1 * cs - k2 * sn);
  kr[base + j + 1024] = (bf16_t)(k2 * cs + k1 * sn);
  vb[base + j]        = (bf16_t)v[base + j];
  vb[base + j + 1024] = (bf16_t)v[base + j + 1024];
}

// ---------------------------------------------------------------------------
// Cast all 4 weight matrices fp32->bf16 in one launch. 8 elems/thread.
// ---------------------------------------------------------------------------
__global__ __launch_bounds__(256) void wcast_kernel(
    const float* __restrict__ w0, const float* __restrict__ w1,
    const float* __restrict__ w2, const float* __restrict__ w3,
    bf16_t* __restrict__ dst) {
  const int wsel = blockIdx.y;
  const float* src = wsel == 0 ? w0 : wsel == 1 ? w1 : wsel == 2 ? w2 : w3;
  const long i = (long)(blockIdx.x * 256 + threadIdx.x) * 8;
  const float4 a = *(const float4*)&src[i];
  const float4 b = *(const float4*)&src[i + 4];
  bf16x8 o;
  o[0] = (bf16_t)a.x; o[1] = (bf16_t)a.y; o[2] = (bf16_t)a.z; o[3] = (bf16_t)a.w;
  o[4] = (bf16_t)b.x; o[5] = (bf16_t)b.y; o[6] = (bf16_t)b.z; o[7] = (bf16_t)b.w;
  *(bf16x8*)&dst[(long)wsel * HDIM * HDIM + i] = o;
}

// ---------------------------------------------------------------------------
// NT GEMM: C[M,N] = alpha * A[M,K] * Bt[N,K]^T + bias
// A,Bt bf16 row-major (lda=ldb=K). Batched via blockIdx.z.
// 128x128 tile, BK=64, 4 waves (2x2), 4x4 16x16x32 MFMA tiles per wave.
// LDS layout: LDS(row, chunk j) = global(row, chunk j ^ (row&7)), chunks = 16B.
// OMODE: 0 = bf16 row-major, 1 = fp32 row-major, 2 = bf16 transposed per batch
//        (vpT[b][col][s], for the V projection; M rows encode b*SDIM+s).
// ---------------------------------------------------------------------------
template <int OMODE>
__global__ __launch_bounds__(256, 2) void gemm_bt(
    const bf16_t* __restrict__ A, const bf16_t* __restrict__ Bt,
    void* __restrict__ Cv, const float* __restrict__ bias,
    int M, int N, int K, float alpha,
    long sA, long sB, long sC) {
  __shared__ __align__(16) bf16_t As[128 * 64];
  __shared__ __align__(16) bf16_t Bs[128 * 64];
  const int z = blockIdx.z;
  A  += (long)z * sA;
  Bt += (long)z * sB;
  const int tid  = threadIdx.x;
  const int lane = tid & 63;
  const int wave = tid >> 6;
  const int wm = (wave >> 1) * 64;   // wave row offset in tile
  const int wn = (wave & 1) * 64;    // wave col offset in tile
  const int m0 = blockIdx.y * 128;
  const int n0 = blockIdx.x * 128;
  const int lrow = lane & 15;
  const int quad = lane >> 4;
  const int swz  = lrow & 7;         // row&7 for all fragment rows this lane reads

  f32x4 acc[4][4] = {};

  const long aBase = (long)m0 * K;
  const long bBase = (long)n0 * K;

  // staging source swizzle: lane writes LDS chunk (lane&7) of row c*8+(lane>>3);
  // load global chunk (lane&7) ^ (lane>>3) so LDS(r,j)=global(r, j^(r&7)).
  const int rl  = lane >> 3;                 // row within 8-row chunk
  const int ccs = ((lane & 7) ^ rl) * 8;     // swizzled global column (elems)

  for (int k0 = 0; k0 < K; k0 += 64) {
#pragma unroll
    for (int i = 0; i < 4; ++i) {
      const int c = wave * 4 + i;            // chunk 0..15, 512 elems each
      const int r = c * 8 + rl;
      async_copy16(A  + aBase + (long)r * K + k0 + ccs, As + c * 512);
      async_copy16(Bt + bBase + (long)r * K + k0 + ccs, Bs + c * 512);
    }
    __syncthreads();
#pragma unroll
    for (int ks = 0; ks < 64; ks += 32) {
      bf16x8 af[4], bfr[4];
      const int cg = (ks >> 3) + quad;       // desired global 16B-chunk index
      const int j  = (cg ^ swz) * 8;         // swizzled LDS column (elems)
#pragma unroll
      for (int t = 0; t < 4; ++t)
        af[t] = *(const bf16x8*)&As[(wm + t * 16 + lrow) * 64 + j];
#pragma unroll
      for (int t = 0; t < 4; ++t)
        bfr[t] = *(const bf16x8*)&Bs[(wn + t * 16 + lrow) * 64 + j];
#pragma unroll
      for (int mt = 0; mt < 4; ++mt)
#pragma unroll
        for (int nt = 0; nt < 4; ++nt)
          acc[mt][nt] = __builtin_amdgcn_mfma_f32_16x16x32_bf16(
              af[mt], bfr[nt], acc[mt][nt], 0, 0, 0);
    }
    __syncthreads();
  }

  // epilogue: D[row=quad*4+r][col=lane&15] per 16x16 tile (HW-verified layout)
#pragma unroll
  for (int mt = 0; mt < 4; ++mt) {
#pragma unroll
    for (int nt = 0; nt < 4; ++nt) {
      const int col = n0 + wn + nt * 16 + lrow;
      const float bv = bias ? bias[col] : 0.0f;
      if (OMODE == 2) {
        // transposed store: 4 consecutive s per lane -> one 8B store
        const int row0 = m0 + wm + mt * 16 + quad * 4;
        const int b = row0 >> 11;            // SDIM = 2048
        const int s = row0 & (SDIM - 1);
        bf16x4 o;
#pragma unroll
        for (int r = 0; r < 4; ++r) o[r] = (bf16_t)(acc[mt][nt][r] + bv);
        *(bf16x4*)&((bf16_t*)Cv)[(long)b * SDIM * HDIM + (long)col * SDIM + s] = o;
      } else {
#pragma unroll
        for (int r = 0; r < 4; ++r) {
          const int row = m0 + wm + mt * 16 + quad * 4 + r;
          const float v = acc[mt][nt][r] * alpha + bv;
          if (OMODE == 1)
            ((float*)Cv)[(long)z * sC + (long)row * N + col] = v;
          else
            ((bf16_t*)Cv)[(long)z * sC + (long)row * N + col] = (bf16_t)v;
        }
      }
    }
  }
}

// ---------------------------------------------------------------------------
// Row softmax: bf16 scores [rows,2048] -> bf16 probs. 256 thr/row, 8 elems/thr.
// ---------------------------------------------------------------------------
__global__ __launch_bounds__(256) void softmax_kernel(
    const bf16_t* __restrict__ Sc, bf16_t* __restrict__ P) {
  const long row = blockIdx.x;
  const bf16_t* src = Sc + row * SDIM;
  bf16_t* dst = P + row * SDIM;
  const int tid = threadIdx.x;
  const bf16x8 in = *(const bf16x8*)&src[tid * 8];
  float x[8];
#pragma unroll
  for (int t = 0; t < 8; ++t) x[t] = (float)in[t];
  float m = x[0];
#pragma unroll
  for (int t = 1; t < 8; ++t) m = fmaxf(m, x[t]);
#pragma unroll
  for (int off = 32; off; off >>= 1) m = fmaxf(m, __shfl_xor(m, off));
  __shared__ float redm[4], reds[4];
  const int wave = tid >> 6, lane = tid & 63;
  if (lane == 0) redm[wave] = m;
  __syncthreads();
  m = fmaxf(fmaxf(redm[0], redm[1]), fmaxf(redm[2], redm[3]));
  float s = 0.0f;
#pragma unroll
  for (int t = 0; t < 8; ++t) { x[t] = __expf(x[t] - m); s += x[t]; }
#pragma unroll
  for (int off = 32; off; off >>= 1) s += __shfl_xor(s, off);
  if (lane == 0) reds[wave] = s;
  __syncthreads();
  s = reds[0] + reds[1] + reds[2] + reds[3];
  const float inv = 1.0f / s;
  bf16x8 o;
#pragma unroll
  for (int t = 0; t < 8; ++t) o[t] = (bf16_t)(x[t] * inv);
  *(bf16x8*)&dst[tid * 8] = o;
}

// ---------------------------------------------------------------------------
extern "C" void kernel_launch(void* const* d_in, const int* in_sizes, int n_in,
                              void* d_out, int out_size, void* d_ws, size_t ws_size,
                              hipStream_t stream) {
  const float* q_in = (const float*)d_in[0];
  const float* k_in = (const float*)d_in[1];
  const float* v_in = (const float*)d_in[2];
  const float* Wq = (const float*)d_in[3];
  const float* bq = (const float*)d_in[4];
  const float* Wk = (const float*)d_in[5];
  const float* bk = (const float*)d_in[6];
  const float* Wv = (const float*)d_in[7];
  const float* bv = (const float*)d_in[8];
  const float* Wo = (const float*)d_in[9];
  const float* bo = (const float*)d_in[10];
  float* out = (float*)d_out;

  const size_t ELE  = (size_t)BDIM * SDIM * HDIM;   // 16,777,216
  const size_t WELE = (size_t)HDIM * HDIM;          // 4,194,304
  const size_t SEG  = ELE * 2;                      // 33,554,432 B per bf16 [B,S,H]

  uint8_t* w = (uint8_t*)d_ws;
  bf16_t* qr  = (bf16_t*)(w + 0 * SEG);
  bf16_t* kr  = (bf16_t*)(w + 1 * SEG);
  bf16_t* vb  = (bf16_t*)(w + 2 * SEG);
  bf16_t* Wb  = (bf16_t*)(w + 3 * SEG);   // Wq,Wk,Wv,Wo bf16 consecutive
  bf16_t* qp  = (bf16_t*)(w + 4 * SEG);
  bf16_t* kp  = (bf16_t*)(w + 5 * SEG);
  bf16_t* vpT = (bf16_t*)(w + 6 * SEG);   // V-proj writes transposed here
  // aliases (regions dead by the time they're written):
  bf16_t* scores = (bf16_t*)(w + 0 * SEG);  // over qr (dead after q-proj)
  bf16_t* probs  = (bf16_t*)(w + 2 * SEG);  // over vb (dead after v-proj)
  bf16_t* ctx    = (bf16_t*)(w + 1 * SEG);  // over kr (dead after k-proj)

  bf16_t* Wqb = Wb + 0 * WELE;
  bf16_t* Wkb = Wb + 1 * WELE;
  bf16_t* Wvb = Wb + 2 * WELE;
  bf16_t* Wob = Wb + 3 * WELE;

  const dim3 blk(256);
  const long SH = (long)SDIM * HDIM;   // per-batch activation stride (elems)
  const long SS = (long)SDIM * SDIM;   // per-batch score stride (elems)

  // 1. RoPE q,k + cast v -> bf16
  prep_kernel<<<dim3(ELE / 2 / 256), blk, 0, stream>>>(q_in, k_in, v_in, qr, kr, vb);
  // 2. weight casts (one launch)
  wcast_kernel<<<dim3(WELE / 8 / 256, 4), blk, 0, stream>>>(Wq, Wk, Wv, Wo, Wb);
  // 3-5. projections: [8192,2048] x [2048,2048]^T + bias
  gemm_bt<0><<<dim3(16, 64, 1), blk, 0, stream>>>(qr, Wqb, qp, bq,
      BDIM * SDIM, HDIM, HDIM, 1.0f, 0, 0, 0);
  gemm_bt<0><<<dim3(16, 64, 1), blk, 0, stream>>>(kr, Wkb, kp, bk,
      BDIM * SDIM, HDIM, HDIM, 1.0f, 0, 0, 0);
  gemm_bt<2><<<dim3(16, 64, 1), blk, 0, stream>>>(vb, Wvb, vpT, bv,
      BDIM * SDIM, HDIM, HDIM, 1.0f, 0, 0, 0);   // writes vpT[b][h][s]
  // 6. scores = qp kp^T / sqrt(H)  (bf16 out, batched)
  gemm_bt<0><<<dim3(16, 16, BDIM), blk, 0, stream>>>(qp, kp, scores, nullptr,
      SDIM, SDIM, HDIM, 0.022097086912079612f, SH, SH, SS);
  // 7. softmax rows -> bf16 probs
  softmax_kernel<<<dim3(BDIM * SDIM), blk, 0, stream>>>(scores, probs);
  // 8. ctx = probs @ vp  ==  NT(probs, vpT)
  gemm_bt<0><<<dim3(16, 16, BDIM), blk, 0, stream>>>(probs, vpT, ctx, nullptr,
      SDIM, HDIM, SDIM, 1.0f, SS, SH, SH);
  // 9. out = ctx Wo^T + bo  (fp32 -> d_out)
  gemm_bt<1><<<dim3(16, 64, 1), blk, 0, stream>>>(ctx, Wob, out, bo,
      BDIM * SDIM, HDIM, HDIM, 1.0f, 0, 0, 0);
}